// Round 11
// baseline (114.971 us; speedup 1.0000x reference)
//
#include <hip/hip_runtime.h>
#include <hip/hip_bf16.h>

// x:[16,64,128,128] f32 -> stats -> MLP -> per-sample kern[64,64,3,3] -> conv(pad=1)
// bf16 MFMA implicit GEMM. xT[b][y][130 xi][64 ci] bf16 (x-padded zero cols).
// wT layout (R11: back to plain): [b][co][tap][ci].
// R11: conv = R5 geometry (64px x 4row tile, 50.7KB LDS -> 2 resident blocks/CU,
// cross-block stage||compute overlap) with the allocator pinned via
// amdgpu_waves_per_eu(4,4) (cap 128) + per-wave weight state cut to 36 regs
// (wave owns ONE 16-co group) + asm-pinned frags. R5's failure was the
// allocator targeting 8 waves/EU (cap 64) and rematerializing the weights.

#define B_ 16
#define NPIX 16384
#define KEL 36864
#define XT_RS 8320          // 130 * 64 shorts per padded row

typedef __attribute__((ext_vector_type(4))) float f32x4;
typedef __attribute__((ext_vector_type(8))) short short8;

static __device__ __forceinline__ short bf16_of(float f) {
    __hip_bfloat16 h = __float2bfloat16(f);
    return *reinterpret_cast<short*>(&h);
}

// ---------- Kernel 1: transpose x -> xT bf16 [b][y][130][64]; partial stats ----------
__global__ __launch_bounds__(256) void xpose_stats(const float* __restrict__ x,
                                                   short* __restrict__ xT,
                                                   float* __restrict__ part) {
    int b = blockIdx.x, cig = blockIdx.y, pt = blockIdx.z;
    int t = threadIdx.x;
    int y = pt * 8 + (t >> 5);
    int x0 = (t & 31) * 4;

    const float* xb = x + ((size_t)(b * 64 + cig * 8)) * NPIX;
    short* xTb = xT + (size_t)b * 128 * XT_RS;

    float s[8], ss[8];
    f32x4 v[8];
    #pragma unroll
    for (int c = 0; c < 8; c++) {
        v[c] = *(const f32x4*)(xb + (size_t)c * NPIX + y * 128 + x0);
        s[c]  = v[c][0] + v[c][1] + v[c][2] + v[c][3];
        ss[c] = v[c][0]*v[c][0] + v[c][1]*v[c][1] + v[c][2]*v[c][2] + v[c][3]*v[c][3];
    }
    #pragma unroll
    for (int xi = 0; xi < 4; xi++) {
        short8 o;
        #pragma unroll
        for (int c = 0; c < 8; c++) o[c] = bf16_of(v[c][xi]);
        *(short8*)(xTb + ((size_t)(y * 130 + x0 + xi + 1)) * 64 + cig * 8) = o;
    }
    // zero-pad columns xi=0 and xi=129 (x halo)
    if (t < 16) {
        int y2 = pt * 8 + (t & 7);
        int col = (t & 8) ? 129 : 0;
        short8 z = {0, 0, 0, 0, 0, 0, 0, 0};
        *(short8*)(xTb + ((size_t)(y2 * 130 + col)) * 64 + cig * 8) = z;
    }

    __shared__ float red[4][16];
    int lane = t & 63, w = t >> 6;
    #pragma unroll
    for (int c = 0; c < 8; c++) {
        float a = s[c], q = ss[c];
        for (int off = 32; off; off >>= 1) { a += __shfl_down(a, off); q += __shfl_down(q, off); }
        if (lane == 0) { red[w][c * 2] = a; red[w][c * 2 + 1] = q; }
    }
    __syncthreads();
    if (t < 16)
        part[((size_t)((b * 8 + cig) * 16 + pt)) * 16 + t] =
            red[0][t] + red[1][t] + red[2][t] + red[3][t];
}

// ---------- Kernel 2: w2 read ONCE; all 16 b per block (grid 144) ----------
__global__ __launch_bounds__(256) void kern_gen(const float* __restrict__ part,
                                                const float* __restrict__ w1,
                                                const float* __restrict__ b1,
                                                const float* __restrict__ w2,
                                                const float* __restrict__ b2,
                                                short* __restrict__ wT) {
    __shared__ float st[16][128];
    __shared__ float hT[32][16];
    int t = threadIdx.x;

    for (int id = t; id < 1024; id += 256) {       // stats for all (b, ci)
        int b = id >> 6, ci = id & 63;
        const float* pb = part + ((size_t)((b * 8 + (ci >> 3)) * 16)) * 16 + (ci & 7) * 2;
        float s = 0.f, q = 0.f;
        #pragma unroll
        for (int p = 0; p < 16; p++) { s += pb[p * 16]; q += pb[p * 16 + 1]; }
        float mean = s * (1.f / NPIX);
        float var = fmaxf((q - s * mean) * (1.f / (NPIX - 1)), 0.f);
        st[b][ci] = mean;
        st[b][64 + ci] = sqrtf(var);
    }
    __syncthreads();
    for (int id = t; id < 512; id += 256) {        // h for all (b, 32), transposed
        int b = id >> 5, jj = id & 31;
        float acc = b1[jj];
        for (int i = 0; i < 128; i++) acc += st[b][i] * w1[i * 32 + jj];
        hT[jj][b] = fmaxf(acc, 0.f);
    }
    __syncthreads();

    int j = blockIdx.x * 256 + t;
    float wv[32];
    #pragma unroll
    for (int i = 0; i < 32; i++) wv[i] = w2[(size_t)i * KEL + j];
    float bv = b2[j];

    float acc[16];
    #pragma unroll
    for (int b = 0; b < 16; b++) acc[b] = bv;
    #pragma unroll
    for (int i = 0; i < 32; i++) {
        float wvi = wv[i];
        const f32x4* hr = (const f32x4*)&hT[i][0];
        #pragma unroll
        for (int q4 = 0; q4 < 4; q4++) {
            f32x4 hq = hr[q4];
            acc[q4 * 4 + 0] += hq[0] * wvi;
            acc[q4 * 4 + 1] += hq[1] * wvi;
            acc[q4 * 4 + 2] += hq[2] * wvi;
            acc[q4 * 4 + 3] += hq[3] * wvi;
        }
    }

    // j = (co*64+ci)*9 + tap; plain layout: wT[b][co][tap][ci]
    int co = j / 576;
    int rem = j - co * 576;
    int ci = rem / 9;
    int tap = rem - ci * 9;
    size_t dst = (size_t)co * 576 + tap * 64 + ci;
    #pragma unroll
    for (int b = 0; b < 16; b++)
        wT[(size_t)b * KEL + dst] = bf16_of(acc[b]);
}

// ---------- Kernel 3: conv via MFMA, 2 resident blocks/CU, weights in VGPR ----------
// grid (b=16, xt=2, yt=32) = 1024 blocks (4/CU, 2 resident -> cross-block overlap).
// 512 thr (8 waves): wave = (cog=w&3, rh=w>>2): 16 co x 2 rows x 64 px.
// Weights: wf0/wf1[9] = 72 VGPR, pinned; acc 2x4xf32x4 = 32. Cap 128 via
// amdgpu_waves_per_eu(4,4). LDS: xls[6][528 slots]x16B = 50688 B only.
__global__ __attribute__((amdgpu_flat_work_group_size(512, 512),
                          amdgpu_waves_per_eu(4, 4)))
void conv_mfma(const short* __restrict__ xT,
               const short* __restrict__ wT,
               float* __restrict__ out) {
    __shared__ __align__(16) short xls[6 * 528 * 8];   // slot = lr*528 + xi*8 + s

    int b = blockIdx.x, xt = blockIdx.y, yt = blockIdx.z;
    int x0 = xt * 64, y0 = yt * 4;
    int t = threadIdx.x;
    int l = t & 63, w = t >> 6;
    int cog = w & 3, rh = w >> 2;
    int l15 = l & 15, lg = l >> 4;

    const short* xTb = xT + (size_t)b * 128 * XT_RS;

    // ---- weight fragment loads (L2-hot; issued first, drained with stage) ----
    const short* wl = wT + (size_t)b * KEL + (cog * 16 + l15) * 576 + lg * 8;
    short8 wf0[9], wf1[9];
    #pragma unroll
    for (int tap = 0; tap < 9; tap++) {
        wf0[tap] = *(const short8*)(wl + tap * 64);        // kp=0 (ci 0..31)
        wf1[tap] = *(const short8*)(wl + tap * 64 + 32);   // kp=1 (ci 32..63)
    }

    // ---- zero OOB halo rows (uniform branches) ----
    if (yt == 0) {
        short8 z8 = {0, 0, 0, 0, 0, 0, 0, 0};
        for (int e = t; e < 528; e += 512) *(short8*)&xls[e * 8] = z8;
    }
    if (yt == 31) {
        short8 z8 = {0, 0, 0, 0, 0, 0, 0, 0};
        for (int e = t; e < 528; e += 512) *(short8*)&xls[(5 * 528 + e) * 8] = z8;
    }

    // ---- stage 6 rows x 66 xi via global_load_lds (swizzled source, linear dest) ----
    #pragma unroll
    for (int it = 0; it < 7; it++) {
        int e = it * 512 + t;
        if (e < 3168) {
            int lr = e / 528;
            int rem = e - lr * 528;
            int xi = rem >> 3, s = rem & 7;
            int y = y0 - 1 + lr;
            if ((unsigned)y < 128u) {
                const short* src = xTb + (size_t)y * XT_RS
                    + (x0 + xi) * 64 + ((s ^ (xi & 7)) << 3);
                __builtin_amdgcn_global_load_lds(
                    (const __attribute__((address_space(1))) void*)src,
                    (__attribute__((address_space(3))) void*)
                        (xls + (it * 512 + (t & ~63)) * 8),
                    16, 0, 0);
            }
        }
    }

    // ---- pin weight frags (need ~115 <= cap 128, safe; blocks remat) ----
    #pragma unroll
    for (int tap = 0; tap < 9; tap++) {
        asm volatile("" : "+v"(wf0[tap]));
        asm volatile("" : "+v"(wf1[tap]));
    }

    asm volatile("s_waitcnt vmcnt(0) lgkmcnt(0)" ::: "memory");
    __builtin_amdgcn_s_barrier();

    f32x4 acc[2][4];                      // [row r][n-tile]
    #pragma unroll
    for (int r = 0; r < 2; r++)
        #pragma unroll
        for (int n = 0; n < 4; n++) acc[r][n] = (f32x4){0.f, 0.f, 0.f, 0.f};

    __builtin_amdgcn_s_setprio(1);
    #pragma unroll
    for (int kp = 0; kp < 2; kp++) {
        int sig = kp * 4 + lg;
        #pragma unroll
        for (int tap = 0; tap < 9; tap++) {
            const int dy = tap / 3, dx = tap % 3;
            short8 a = kp ? wf1[tap] : wf0[tap];
            #pragma unroll
            for (int r = 0; r < 2; r++) {
                int lr = rh * 2 + r + dy;             // 0..5
                #pragma unroll
                for (int n = 0; n < 4; n++) {
                    int xi = n * 16 + l15 + dx;       // 0..65
                    short8 bf = *(const short8*)&xls[(lr * 528 + xi * 8 + (sig ^ (xi & 7))) * 8];
                    acc[r][n] = __builtin_amdgcn_mfma_f32_16x16x32_bf16(a, bf, acc[r][n], 0, 0, 0);
                }
            }
        }
    }
    __builtin_amdgcn_s_setprio(0);

    // ---- store: 16 co (cog) x 2 rows x 64 px ----
    #pragma unroll
    for (int reg = 0; reg < 4; reg++) {
        float* ob = out + ((size_t)(b * 64 + cog * 16 + lg * 4 + reg)) * NPIX
                        + (y0 + rh * 2) * 128 + x0 + l15;
        #pragma unroll
        for (int r = 0; r < 2; r++)
            #pragma unroll
            for (int n = 0; n < 4; n++)
                ob[r * 128 + n * 16] = acc[r][n][reg];
    }
}

extern "C" void kernel_launch(void* const* d_in, const int* in_sizes, int n_in,
                              void* d_out, int out_size, void* d_ws, size_t ws_size,
                              hipStream_t stream) {
    const float* x  = (const float*)d_in[0];
    const float* w1 = (const float*)d_in[1];
    const float* b1 = (const float*)d_in[2];
    const float* w2 = (const float*)d_in[3];
    const float* b2 = (const float*)d_in[4];
    float* out = (float*)d_out;

    float* part = (float*)d_ws;                                   // 128 KB
    short* wT = (short*)((char*)d_ws + 131072);                   // 1.18 MB
    short* xT = (short*)((char*)d_ws + 131072 + 1179648);         // 34.1 MB

    xpose_stats<<<dim3(B_, 8, 16), 256, 0, stream>>>(x, xT, part);
    kern_gen<<<dim3(144), 256, 0, stream>>>(part, w1, b1, w2, b2, wT);
    conv_mfma<<<dim3(B_, 2, 32), 512, 0, stream>>>(xT, wT, out);
}